// Round 6
// baseline (383.151 us; speedup 1.0000x reference)
//
#include <hip/hip_runtime.h>
#include <math.h>

// ---------- types / helpers ----------
typedef short s8x __attribute__((ext_vector_type(8)));   // 8 bf16 (4 VGPRs) MFMA A/B frag
typedef float f32x4 __attribute__((ext_vector_type(4))); // MFMA C/D frag

__device__ __forceinline__ float bf2f(short u) {
    return __uint_as_float(((unsigned int)(unsigned short)u) << 16);
}
__device__ __forceinline__ short f2bf(float f) {
    unsigned int x = __float_as_uint(f);
    unsigned int r = (x + 0x7FFFu + ((x >> 16) & 1u)) >> 16; // RNE
    return (short)(unsigned short)r;
}

// async global->LDS, 16B per lane. LDS dest must be wave-uniform base + lane*16.
__device__ __forceinline__ void gl2lds16(const short* g, const short* l) {
    __builtin_amdgcn_global_load_lds(
        (const __attribute__((address_space(1))) void*)(unsigned long long)g,
        (__attribute__((address_space(3))) void*)(unsigned int)(unsigned long long)l,
        16, 0, 0);
}

// ---------- fused weight transpose+downcast: 4 weights, one dispatch ----------
__global__ __launch_bounds__(256) void transpose_all_k(
        const float* __restrict__ w0, const float* __restrict__ w1,
        const float* __restrict__ w2, const float* __restrict__ w3,
        short* __restrict__ o0, short* __restrict__ o1,
        short* __restrict__ o2, short* __restrict__ o3) {
    int bid = blockIdx.x;
    const float* in; short* out; int K, N, nx;
    if (bid < 3072)      { in = w0; out = o0; K = 1024; N = 3072; nx = 96; }
    else if (bid < 4096) { bid -= 3072; in = w1; out = o1; K = 1024; N = 1024; nx = 32; }
    else if (bid < 8192) { bid -= 4096; in = w2; out = o2; K = 1024; N = 4096; nx = 128; }
    else                 { bid -= 8192; in = w3; out = o3; K = 4096; N = 1024; nx = 32; }
    const int n0 = (bid % nx) * 32, k0 = (bid / nx) * 32;
    __shared__ float tile[32][33];
    const int tx = threadIdx.x & 31, ty = threadIdx.x >> 5; // ty 0..7
#pragma unroll
    for (int i = 0; i < 4; ++i) {
        const int k = ty + i * 8;
        tile[k][tx] = in[(long)(k0 + k) * N + n0 + tx];
    }
    __syncthreads();
#pragma unroll
    for (int i = 0; i < 4; ++i) {
        const int n = ty + i * 8;
        out[(long)(n0 + n) * K + k0 + tx] = f2bf(tile[tx][n]);
    }
}

// ---------- LayerNorm: f32 in -> bf16 out, one block per row, C=1024 ----------
__global__ __launch_bounds__(256) void ln_k(const float* __restrict__ xin,
                                            const float* __restrict__ w,
                                            const float* __restrict__ bb,
                                            short* __restrict__ out) {
    const int row = blockIdx.x, tid = threadIdx.x;
    const float4 t = ((const float4*)(xin + (long)row * 1024))[tid];
    float v[4] = {t.x, t.y, t.z, t.w};
    float s1 = v[0] + v[1] + v[2] + v[3];
    float s2 = v[0]*v[0] + v[1]*v[1] + v[2]*v[2] + v[3]*v[3];
#pragma unroll
    for (int off = 32; off > 0; off >>= 1) {
        s1 += __shfl_xor(s1, off, 64);
        s2 += __shfl_xor(s2, off, 64);
    }
    __shared__ float red[8];
    if ((tid & 63) == 0) { red[(tid >> 6)*2] = s1; red[(tid >> 6)*2 + 1] = s2; }
    __syncthreads();
    const float t1 = red[0] + red[2] + red[4] + red[6];
    const float t2 = red[1] + red[3] + red[5] + red[7];
    const float mu = t1 * (1.0f / 1024.0f);
    float var = t2 * (1.0f / 1024.0f) - mu * mu;
    var = fmaxf(var, 0.0f);
    const float rs = rsqrtf(var + 1e-5f);
    const int ci = tid * 4;
    short4 o;
    o.x = f2bf((v[0] - mu) * rs * w[ci+0] + bb[ci+0]);
    o.y = f2bf((v[1] - mu) * rs * w[ci+1] + bb[ci+1]);
    o.z = f2bf((v[2] - mu) * rs * w[ci+2] + bb[ci+2]);
    o.w = f2bf((v[3] - mu) * rs * w[ci+3] + bb[ci+3]);
    ((short4*)(out + (long)row * 1024))[tid] = o;
}

// ---------- GEMM epilogue ----------
// EPI 1 GELU: tanh-form (sigmoid identity), |delta vs exact erf| < 3e-3 << bf16 tol.
template <int EPI, typename OutT>
__device__ __forceinline__ void epi_store(OutT* out, const float* resid, long oidx, float v) {
    if constexpr (EPI == 0) {
        out[oidx] = f2bf(v);
    } else if constexpr (EPI == 1) {
        const float u = v * (0.79788456080f + 0.03567740814f * v * v);
        v = v / (1.0f + __expf(-2.0f * u));
        out[oidx] = f2bf(v);
    } else {
        v += resid[oidx];
        out[oidx] = v;   // f32 store
    }
}

// ---------- GEMM 128x128, BK=32, double-buffered, 1 barrier/step ----------
template <int EPI, typename OutT>
__global__ __launch_bounds__(256) void gemm_k(const short* __restrict__ A,
                                              const short* __restrict__ Bt,
                                              const float* __restrict__ bias,
                                              const float* __restrict__ resid,
                                              OutT* __restrict__ out,
                                              int M, int N, int K) {
    __shared__ __align__(16) short sA[2][128 * 32];
    __shared__ __align__(16) short sB[2][128 * 32];
    const int tid = threadIdx.x;
    const int lane = tid & 63, wave = tid >> 6;
    const int wr = (wave >> 1) * 64, wc = (wave & 1) * 64;
    const int lrow = lane & 15, quad = lane >> 4;
    const int bm = blockIdx.y * 128, bn = blockIdx.x * 128;
    const short* Ap = A + (long)(bm + (tid >> 2)) * K + (tid & 3) * 8;
    const short* Bp = Bt + (long)(bn + (tid >> 2)) * K + (tid & 3) * 8;
    const long rowstep = (long)64 * K;

    auto stage = [&](int p, int k0) {
        gl2lds16(Ap + k0,           sA[p] + tid * 8);
        gl2lds16(Ap + rowstep + k0, sA[p] + 2048 + tid * 8);
        gl2lds16(Bp + k0,           sB[p] + tid * 8);
        gl2lds16(Bp + rowstep + k0, sB[p] + 2048 + tid * 8);
    };

    f32x4 acc[4][4] = {};
    stage(0, 0);
    const int S = K >> 5;
    for (int s = 0; s < S; ++s) {
        const int p = s & 1;
        __syncthreads();                          // drains my prefetch (hidden by prev MFMAs)
        if (s + 1 < S) stage(p ^ 1, (s + 1) << 5);
        const short* pA = sA[p];
        const short* pB = sB[p];
        s8x af[4], bfr[4];
#pragma unroll
        for (int i = 0; i < 4; ++i) af[i]  = *(const s8x*)(pA + (wr + i*16 + lrow) * 32 + quad * 8);
#pragma unroll
        for (int j = 0; j < 4; ++j) bfr[j] = *(const s8x*)(pB + (wc + j*16 + lrow) * 32 + quad * 8);
#pragma unroll
        for (int i = 0; i < 4; ++i)
#pragma unroll
            for (int j = 0; j < 4; ++j)
                acc[i][j] = __builtin_amdgcn_mfma_f32_16x16x32_bf16(af[i], bfr[j], acc[i][j], 0, 0, 0);
    }
#pragma unroll
    for (int i = 0; i < 4; ++i) {
#pragma unroll
        for (int j = 0; j < 4; ++j) {
#pragma unroll
            for (int r = 0; r < 4; ++r) {
                const int row = bm + wr + i*16 + quad*4 + r;   // C/D: row = quad*4 + reg
                const int col = bn + wc + j*16 + lrow;         // C/D: col = lane&15
                epi_store<EPI>(out, resid, (long)row * N + col, acc[i][j][r] + bias[col]);
            }
        }
    }
}

// ---------- GEMM 64x128, BK=64 (2x32 panels), double-buffered, 1 barrier/step ----------
template <int EPI, typename OutT>
__global__ __launch_bounds__(256) void gemm64_k(const short* __restrict__ A,
                                                const short* __restrict__ Bt,
                                                const float* __restrict__ bias,
                                                const float* __restrict__ resid,
                                                OutT* __restrict__ out,
                                                int M, int N, int K) {
    __shared__ __align__(16) short sA[2][2][64 * 32];
    __shared__ __align__(16) short sB[2][2][128 * 32];
    const int tid = threadIdx.x;
    const int lane = tid & 63, wave = tid >> 6;
    const int lrow = lane & 15, quad = lane >> 4;
    const int bm = blockIdx.y * 64, bn = blockIdx.x * 128;
    const short* Ap = A + (long)(bm + (tid >> 2)) * K + (tid & 3) * 8;
    const short* Bp = Bt + (long)(bn + (tid >> 2)) * K + (tid & 3) * 8;
    const long rowstep = (long)64 * K;

    auto stage = [&](int p, int k0) {
#pragma unroll
        for (int hp = 0; hp < 2; ++hp) {
            gl2lds16(Ap + k0 + hp * 32,           sA[p][hp] + tid * 8);
            gl2lds16(Bp + k0 + hp * 32,           sB[p][hp] + tid * 8);
            gl2lds16(Bp + rowstep + k0 + hp * 32, sB[p][hp] + 2048 + tid * 8);
        }
    };

    f32x4 acc[8] = {};
    stage(0, 0);
    const int S = K >> 6;
    for (int s = 0; s < S; ++s) {
        const int p = s & 1;
        __syncthreads();
        if (s + 1 < S) stage(p ^ 1, (s + 1) << 6);
#pragma unroll
        for (int hp = 0; hp < 2; ++hp) {
            const s8x af = *(const s8x*)(sA[p][hp] + (wave * 16 + lrow) * 32 + quad * 8);
#pragma unroll
            for (int j = 0; j < 8; ++j) {
                const s8x bf = *(const s8x*)(sB[p][hp] + (j * 16 + lrow) * 32 + quad * 8);
                acc[j] = __builtin_amdgcn_mfma_f32_16x16x32_bf16(af, bf, acc[j], 0, 0, 0);
            }
        }
    }
#pragma unroll
    for (int j = 0; j < 8; ++j) {
#pragma unroll
        for (int r = 0; r < 4; ++r) {
            const int row = bm + wave * 16 + quad * 4 + r;
            const int col = bn + j * 16 + lrow;
            epi_store<EPI>(out, resid, (long)row * N + col, acc[j][r] + bias[col]);
        }
    }
}

// ---------- attention common constants ----------
#define ATT_CS (0.125f * 1.4426950408889634f)  /* log2(e)/sqrt(64) */
#define ATT_C0 (14.426950408889634f)           /* 10*log2(e) fixed shift */

// ---------- K-split flash attention (chunked, additive combine) ----------
// grid (32 qt, 32 bh, 2 chunk). Each block: one 64-row q-tile, half the key range.
// No online max -> partial (O, l) are additive. O partial bf16 -> ws, l f32 -> ws.
__global__ __launch_bounds__(256) void attn_split_k(const short* __restrict__ qkv,
                                                    short* __restrict__ Opart,
                                                    float* __restrict__ lpart) {
    const int qt = blockIdx.x, bh = blockIdx.y, c = blockIdx.z;
    const int b = bh >> 4, h = bh & 15;
    const int half = (qt + 2) >> 1;
    const int kb = c == 0 ? 0 : half;
    const int ke = c == 0 ? half : qt + 1;
    const int tid = threadIdx.x, lane = tid & 63, wave = tid >> 6;
    const int lrow = lane & 15, quad = lane >> 4;
    const long base = (long)b * 2048 * 3072;
    const int tile = bh * 32 + qt;

    __shared__ __align__(16) short sK[2][64 * 64];
    __shared__ __align__(16) short sVt[2][64 * 64];
    __shared__ __align__(16) short sP[64 * 72];

    f32x4 o[4] = {}, lacc = {};
    s8x ones;
#pragma unroll
    for (int j = 0; j < 8; ++j) ones[j] = (short)0x3F80;   // bf16 1.0

    if (ke > kb) {
        s8x qf0, qf1;
        {
            const short* qp = qkv + base + (long)(qt * 64 + wave * 16 + lrow) * 3072 + h * 64 + quad * 8;
            qf0 = *(const s8x*)qp; qf1 = *(const s8x*)(qp + 32);
        }
        const int srow = tid >> 3;          // 0..31
        const int sg   = tid & 7;           // 8-elem group
        const int sw0 = ((srow & 7) ^ (srow >> 3)) & 7;
        const int sw1 = (((srow + 32) & 7) ^ ((srow + 32) >> 3)) & 7;
        const short* kbase = qkv + base + 1024 + h * 64;
        const short* vbase = qkv + base + 2048 + h * 64;

        uint4 vr0, vr1;
        auto issueK = [&](int p, int k0) {
            gl2lds16(kbase + (long)(k0 + srow) * 3072      + (sg ^ sw0) * 8, sK[p] + tid * 8);
            gl2lds16(kbase + (long)(k0 + srow + 32) * 3072 + (sg ^ sw1) * 8, sK[p] + 2048 + tid * 8);
        };
        auto loadV = [&](int k0) {
            const short* vp = vbase + (long)(k0 + srow) * 3072 + sg * 8;
            vr0 = *(const uint4*)vp;
            vr1 = *(const uint4*)(vp + 32 * 3072);
        };
        auto writeV = [&](int p) {
            const short* e0 = (const short*)&vr0;
            const short* e1 = (const short*)&vr1;
#pragma unroll
            for (int i = 0; i < 8; ++i) {
                const int d = sg * 8 + i;
                const int swd = i ^ sg;
                sVt[p][d * 64 + ( srow       ^ (swd << 3))] = e0[i];
                sVt[p][d * 64 + ((srow + 32) ^ (swd << 3))] = e1[i];
            }
        };

        issueK(0, kb * 64);
        loadV(kb * 64);
        for (int kt = kb; kt < ke; ++kt) {
            const int p = (kt - kb) & 1, k0 = kt * 64;
            writeV(p);
            __syncthreads();
            if (kt + 1 < ke) { issueK(p ^ 1, k0 + 64); loadV(k0 + 64); }

            s8x kf0[4], kf1[4];
#pragma unroll
            for (int ct = 0; ct < 4; ++ct) {
                const int row = ct * 16 + lrow;
                const int swr = ((row & 7) ^ (row >> 3)) & 7;
                kf0[ct] = *(const s8x*)(sK[p] + row * 64 + ((quad ^ swr) * 8));
                kf1[ct] = *(const s8x*)(sK[p] + row * 64 + (((4 + quad) ^ swr) * 8));
            }
            f32x4 s[4];
#pragma unroll
            for (int ct = 0; ct < 4; ++ct) {
                f32x4 t = f32x4{0.f, 0.f, 0.f, 0.f};
                t = __builtin_amdgcn_mfma_f32_16x16x32_bf16(qf0, kf0[ct], t, 0, 0, 0);
                t = __builtin_amdgcn_mfma_f32_16x16x32_bf16(qf1, kf1[ct], t, 0, 0, 0);
                s[ct] = t;
            }
            if (kt == qt) {           // diagonal tile masking (uniform branch)
                const int qrow = qt * 64 + wave * 16 + quad * 4;
#pragma unroll
                for (int ct = 0; ct < 4; ++ct) {
                    const int key = k0 + ct * 16 + lrow;
#pragma unroll
                    for (int r = 0; r < 4; ++r) {
                        const float e = (key > qrow + r) ? -1e30f : fmaf(s[ct][r], ATT_CS, -ATT_C0);
                        s[ct][r] = exp2f(e);
                    }
                }
            } else {
#pragma unroll
                for (int ct = 0; ct < 4; ++ct)
#pragma unroll
                    for (int r = 0; r < 4; ++r)
                        s[ct][r] = exp2f(fmaf(s[ct][r], ATT_CS, -ATT_C0));
            }
#pragma unroll
            for (int ct = 0; ct < 4; ++ct)
#pragma unroll
                for (int r = 0; r < 4; ++r)
                    sP[(wave * 16 + quad * 4 + r) * 72 + ct * 16 + lrow] = f2bf(s[ct][r]);
#pragma unroll
            for (int ks = 0; ks < 2; ++ks) {
                const s8x pf = *(const s8x*)(sP + (wave * 16 + lrow) * 72 + ks * 32 + quad * 8);
                lacc = __builtin_amdgcn_mfma_f32_16x16x32_bf16(pf, ones, lacc, 0, 0, 0);
#pragma unroll
                for (int dt = 0; dt < 4; ++dt) {
                    const int d = dt * 16 + lrow;
                    const int swd = ((d & 7) ^ (d >> 3)) & 7;
                    const s8x vf = *(const s8x*)(sVt[p] + d * 64 + (((ks * 4 + quad) ^ swd) * 8));
                    o[dt] = __builtin_amdgcn_mfma_f32_16x16x32_bf16(pf, vf, o[dt], 0, 0, 0);
                }
            }
        }
    }
    // write partial O (bf16) and l (f32)
    const long pbase = ((long)c * 1024 + tile) * 4096;   // 64 rows * 64 d
#pragma unroll
    for (int dt = 0; dt < 4; ++dt) {
#pragma unroll
        for (int r = 0; r < 4; ++r) {
            const int row = wave * 16 + quad * 4 + r;
            Opart[pbase + row * 64 + dt * 16 + lrow] = f2bf(o[dt][r]);
        }
    }
    if (lrow == 0) {
#pragma unroll
        for (int r = 0; r < 4; ++r)
            lpart[(long)c * 65536 + tile * 64 + wave * 16 + quad * 4 + r] = lacc[r];
    }
}

// ---------- combine partial chunks -> y (bf16) ----------
__global__ __launch_bounds__(256) void attn_combine_k(const short* __restrict__ Opart,
                                                      const float* __restrict__ lpart,
                                                      short* __restrict__ y) {
    const int blk = blockIdx.x;            // 0..4095
    const int tile = blk >> 2;             // bh*32 + qt
    const int tid = threadIdx.x;
    const int row = (blk & 3) * 16 + (tid >> 4);
    const int d4 = (tid & 15) * 4;
    const int bh = tile >> 5, qt = tile & 31;
    const int b = bh >> 4, h = bh & 15;
    const long po = ((long)tile * 64 + row) * 64 + d4;
    const short4 o0 = *(const short4*)(Opart + po);
    const short4 o1 = *(const short4*)(Opart + 4194304L + po);
    const int li = tile * 64 + row;
    const float rl = 1.0f / (lpart[li] + lpart[65536 + li]);
    short4 ov;
    ov.x = f2bf((bf2f(o0.x) + bf2f(o1.x)) * rl);
    ov.y = f2bf((bf2f(o0.y) + bf2f(o1.y)) * rl);
    ov.z = f2bf((bf2f(o0.z) + bf2f(o1.z)) * rl);
    ov.w = f2bf((bf2f(o0.w) + bf2f(o1.w)) * rl);
    *(short4*)(y + ((long)(b * 2048 + qt * 64 + row)) * 1024 + h * 64 + d4) = ov;
}

// ---------- fallback: paired-tile flash attention (round-5 version) ----------
__global__ __launch_bounds__(256) void attn_k(const short* __restrict__ qkv,
                                              short* __restrict__ y) {
    const int bx = blockIdx.x;                 // 0..15
    const int b = blockIdx.y >> 4, h = blockIdx.y & 15;
    const int qtA = bx, qtB = 31 - bx;
    const int tid = threadIdx.x, lane = tid & 63, wave = tid >> 6;
    const int lrow = lane & 15, quad = lane >> 4;
    const long base = (long)b * 2048 * 3072;

    __shared__ __align__(16) short sK[2][64 * 64];
    __shared__ __align__(16) short sVt[2][64 * 64];
    __shared__ __align__(16) short sP[64 * 72];

    s8x qfA0, qfA1, qfB0, qfB1;
    {
        const short* qpA = qkv + base + (long)(qtA * 64 + wave * 16 + lrow) * 3072 + h * 64 + quad * 8;
        qfA0 = *(const s8x*)qpA; qfA1 = *(const s8x*)(qpA + 32);
        const short* qpB = qkv + base + (long)(qtB * 64 + wave * 16 + lrow) * 3072 + h * 64 + quad * 8;
        qfB0 = *(const s8x*)qpB; qfB1 = *(const s8x*)(qpB + 32);
    }
    f32x4 oA[4], oB[4], lA = {}, lB = {};
#pragma unroll
    for (int d = 0; d < 4; ++d) { oA[d] = f32x4{0.f,0.f,0.f,0.f}; oB[d] = f32x4{0.f,0.f,0.f,0.f}; }
    s8x ones;
#pragma unroll
    for (int j = 0; j < 8; ++j) ones[j] = (short)0x3F80;

    const int srow = tid >> 3, sg = tid & 7;
    const int sw0 = ((srow & 7) ^ (srow >> 3)) & 7;
    const int sw1 = (((srow + 32) & 7) ^ ((srow + 32) >> 3)) & 7;
    const short* kbase = qkv + base + 1024 + h * 64;
    const short* vbase = qkv + base + 2048 + h * 64;

    uint4 vr0, vr1;
    auto issueK = [&](int p, int k0) {
        gl2lds16(kbase + (long)(k0 + srow) * 3072      + (sg ^ sw0) * 8, sK[p] + tid * 8);
        gl2lds16(kbase + (long)(k0 + srow + 32) * 3072 + (sg ^ sw1) * 8, sK[p] + 2048 + tid * 8);
    };
    auto loadV = [&](int k0) {
        const short* vp = vbase + (long)(k0 + srow) * 3072 + sg * 8;
        vr0 = *(const uint4*)vp;
        vr1 = *(const uint4*)(vp + 32 * 3072);
    };
    auto writeV = [&](int p) {
        const short* e0 = (const short*)&vr0;
        const short* e1 = (const short*)&vr1;
#pragma unroll
        for (int i = 0; i < 8; ++i) {
            const int d = sg * 8 + i;
            const int swd = i ^ sg;
            sVt[p][d * 64 + ( srow       ^ (swd << 3))] = e0[i];
            sVt[p][d * 64 + ((srow + 32) ^ (swd << 3))] = e1[i];
        }
    };

    auto tile_step = [&](const s8x& qf0, const s8x& qf1, const s8x* kf0, const s8x* kf1,
                         const short* pV, f32x4* o, f32x4& lacc, int qt, int kt, int k0) {
        f32x4 s[4];
#pragma unroll
        for (int ct = 0; ct < 4; ++ct) {
            f32x4 t = f32x4{0.f, 0.f, 0.f, 0.f};
            t = __builtin_amdgcn_mfma_f32_16x16x32_bf16(qf0, kf0[ct], t, 0, 0, 0);
            t = __builtin_amdgcn_mfma_f32_16x16x32_bf16(qf1, kf1[ct], t, 0, 0, 0);
            s[ct] = t;
        }
        if (kt == qt) {
            const int qrow = qt * 64 + wave * 16 + quad * 4;
#pragma unroll
            for (int ct = 0; ct < 4; ++ct) {
                const int key = k0 + ct * 16 + lrow;
#pragma unroll
                for (int r = 0; r < 4; ++r) {
                    const float e = (key > qrow + r) ? -1e30f : fmaf(s[ct][r], ATT_CS, -ATT_C0);
                    s[ct][r] = exp2f(e);
                }
            }
        } else {
#pragma unroll
            for (int ct = 0; ct < 4; ++ct)
#pragma unroll
                for (int r = 0; r < 4; ++r)
                    s[ct][r] = exp2f(fmaf(s[ct][r], ATT_CS, -ATT_C0));
        }
#pragma unroll
        for (int ct = 0; ct < 4; ++ct)
#pragma unroll
            for (int r = 0; r < 4; ++r)
                sP[(wave * 16 + quad * 4 + r) * 72 + ct * 16 + lrow] = f2bf(s[ct][r]);
#pragma unroll
        for (int ks = 0; ks < 2; ++ks) {
            const s8x pf = *(const s8x*)(sP + (wave * 16 + lrow) * 72 + ks * 32 + quad * 8);
            lacc = __builtin_amdgcn_mfma_f32_16x16x32_bf16(pf, ones, lacc, 0, 0, 0);
#pragma unroll
            for (int dt = 0; dt < 4; ++dt) {
                const int d = dt * 16 + lrow;
                const int swd = ((d & 7) ^ (d >> 3)) & 7;
                const s8x vf = *(const s8x*)(pV + d * 64 + (((ks * 4 + quad) ^ swd) * 8));
                o[dt] = __builtin_amdgcn_mfma_f32_16x16x32_bf16(pf, vf, o[dt], 0, 0, 0);
            }
        }
    };

    issueK(0, 0);
    loadV(0);
    for (int kt = 0; kt <= qtB; ++kt) {
        const int p = kt & 1, k0 = kt * 64;
        writeV(p);
        __syncthreads();
        if (kt < qtB) { issueK(p ^ 1, k0 + 64); loadV(k0 + 64); }

        s8x kf0[4], kf1[4];
#pragma unroll
        for (int ct = 0; ct < 4; ++ct) {
            const int row = ct * 16 + lrow;
            const int swr = ((row & 7) ^ (row >> 3)) & 7;
            kf0[ct] = *(const s8x*)(sK[p] + row * 64 + ((quad ^ swr) * 8));
            kf1[ct] = *(const s8x*)(sK[p] + row * 64 + (((4 + quad) ^ swr) * 8));
        }
        if (kt <= qtA) tile_step(qfA0, qfA1, kf0, kf1, sVt[p], oA, lA, qtA, kt, k0);
        tile_step(qfB0, qfB1, kf0, kf1, sVt[p], oB, lB, qtB, kt, k0);
    }
    float rA[4], rB[4];
#pragma unroll
    for (int r = 0; r < 4; ++r) { rA[r] = 1.0f / lA[r]; rB[r] = 1.0f / lB[r]; }
#pragma unroll
    for (int dt = 0; dt < 4; ++dt) {
#pragma unroll
        for (int r = 0; r < 4; ++r) {
            const int qA = qtA * 64 + wave * 16 + quad * 4 + r;
            const int qB = qtB * 64 + wave * 16 + quad * 4 + r;
            y[((long)b * 2048 + qA) * 1024 + h * 64 + dt * 16 + lrow] = f2bf(oA[dt][r] * rA[r]);
            y[((long)b * 2048 + qB) * 1024 + h * 64 + dt * 16 + lrow] = f2bf(oB[dt][r] * rB[r]);
        }
    }
}

// ---------- launch ----------
extern "C" void kernel_launch(void* const* d_in, const int* in_sizes, int n_in,
                              void* d_out, int out_size, void* d_ws, size_t ws_size,
                              hipStream_t stream) {
    const float* x      = (const float*)d_in[0];
    const float* ln1_w  = (const float*)d_in[1];
    const float* ln1_b  = (const float*)d_in[2];
    const float* attn_w = (const float*)d_in[3];
    const float* attn_b = (const float*)d_in[4];
    const float* proj_w = (const float*)d_in[5];
    const float* proj_b = (const float*)d_in[6];
    const float* ln2_w  = (const float*)d_in[7];
    const float* ln2_b  = (const float*)d_in[8];
    const float* fc_w   = (const float*)d_in[9];
    const float* fc_b   = (const float*)d_in[10];
    const float* mlp_w  = (const float*)d_in[11];
    const float* mlp_b  = (const float*)d_in[12];

    char* ws = (char*)d_ws;
    short* attn_wt = (short*)(ws + 0);           // [3072,1024] bf16
    short* proj_wt = (short*)(ws + 6291456L);    // [1024,1024] bf16
    short* fc_wt   = (short*)(ws + 8388608L);    // [4096,1024] bf16
    short* mlp_wt  = (short*)(ws + 16777216L);   // [1024,4096] bf16
    short* slotA   = (short*)(ws + 25165824L);   // xln / y / h  [4096,1024] bf16
    short* slotB   = (short*)(ws + 33554432L);   // qkv [4096,3072] / hh [4096,4096] bf16
    short* Opart   = (short*)(ws + 67108864L);   // [2][1024][64][64] bf16  16,777,216 B
    float* lpart   = (float*)(ws + 83886080L);   // [2][1024][64] f32          524,288 B
    // split path needs 84,410,368 B of ws

    short* xln  = slotA;
    short* yb   = slotA;
    short* hb   = slotA;
    short* qkvb = slotB;
    short* hh   = slotB;
    float* x1   = (float*)d_out;   // f32 residual stream lives in d_out
    float* outp = (float*)d_out;

    const bool use_split = (ws_size >= 84410368ULL);

    transpose_all_k<<<12288, 256, 0, stream>>>(attn_w, proj_w, fc_w, mlp_w,
                                               attn_wt, proj_wt, fc_wt, mlp_wt);

    ln_k<<<4096, 256, 0, stream>>>(x, ln1_w, ln1_b, xln);
    gemm_k<0, short><<<dim3(24, 32), 256, 0, stream>>>(xln, attn_wt, attn_b, nullptr, qkvb, 4096, 3072, 1024);
    if (use_split) {
        attn_split_k<<<dim3(32, 32, 2), 256, 0, stream>>>(qkvb, Opart, lpart);
        attn_combine_k<<<4096, 256, 0, stream>>>(Opart, lpart, yb);
    } else {
        attn_k<<<dim3(16, 32), 256, 0, stream>>>(qkvb, yb);
    }
    gemm64_k<2, float><<<dim3(8, 64), 256, 0, stream>>>(yb, proj_wt, proj_b, x, x1, 4096, 1024, 1024);
    ln_k<<<4096, 256, 0, stream>>>(x1, ln2_w, ln2_b, hb);
    gemm_k<1, short><<<dim3(32, 32), 256, 0, stream>>>(hb, fc_wt, fc_b, nullptr, hh, 4096, 4096, 1024);
    gemm64_k<3, float><<<dim3(8, 64), 256, 0, stream>>>(hh, mlp_wt, mlp_b, x1, outp, 4096, 1024, 4096);
}

// Round 7
// 334.421 us; speedup vs baseline: 1.1457x; 1.1457x over previous
//
#include <hip/hip_runtime.h>
#include <math.h>

// ---------- types / helpers ----------
typedef short s8x __attribute__((ext_vector_type(8)));   // 8 bf16 (4 VGPRs) MFMA A/B frag
typedef float f32x4 __attribute__((ext_vector_type(4))); // MFMA C/D frag

__device__ __forceinline__ float bf2f(short u) {
    return __uint_as_float(((unsigned int)(unsigned short)u) << 16);
}
__device__ __forceinline__ short f2bf(float f) {
    unsigned int x = __float_as_uint(f);
    unsigned int r = (x + 0x7FFFu + ((x >> 16) & 1u)) >> 16; // RNE
    return (short)(unsigned short)r;
}
__device__ __forceinline__ short f2bf_trunc(float f) {      // truncate: P>=0, bias cancels in O/l
    return (short)(__float_as_uint(f) >> 16);
}

// async global->LDS, 16B per lane. LDS dest must be wave-uniform base + lane*16.
__device__ __forceinline__ void gl2lds16(const short* g, const short* l) {
    __builtin_amdgcn_global_load_lds(
        (const __attribute__((address_space(1))) void*)(unsigned long long)g,
        (__attribute__((address_space(3))) void*)(unsigned int)(unsigned long long)l,
        16, 0, 0);
}

// ---------- wave-per-row LayerNorm core: f32 in -> bf16 out, C=1024 ----------
__device__ __forceinline__ void ln_row(const float* __restrict__ xin,
                                       const float* __restrict__ w,
                                       const float* __restrict__ bb,
                                       short* __restrict__ out, int row, int lane) {
    const float4* xr = (const float4*)(xin + (long)row * 1024);
    float4 v[4];
    float s1 = 0.f, s2 = 0.f;
#pragma unroll
    for (int i = 0; i < 4; ++i) {
        v[i] = xr[lane + i * 64];
        s1 += v[i].x + v[i].y + v[i].z + v[i].w;
        s2 += v[i].x*v[i].x + v[i].y*v[i].y + v[i].z*v[i].z + v[i].w*v[i].w;
    }
#pragma unroll
    for (int off = 32; off > 0; off >>= 1) {
        s1 += __shfl_xor(s1, off, 64);
        s2 += __shfl_xor(s2, off, 64);
    }
    const float mu = s1 * (1.0f / 1024.0f);
    float var = s2 * (1.0f / 1024.0f) - mu * mu;
    var = fmaxf(var, 0.0f);
    const float rs = rsqrtf(var + 1e-5f);
    short4* orow = (short4*)(out + (long)row * 1024);
#pragma unroll
    for (int i = 0; i < 4; ++i) {
        const int ci = (lane + i * 64) * 4;
        const float4 wv = *(const float4*)(w + ci);
        const float4 bv = *(const float4*)(bb + ci);
        short4 o;
        o.x = f2bf((v[i].x - mu) * rs * wv.x + bv.x);
        o.y = f2bf((v[i].y - mu) * rs * wv.y + bv.y);
        o.z = f2bf((v[i].z - mu) * rs * wv.z + bv.z);
        o.w = f2bf((v[i].w - mu) * rs * wv.w + bv.w);
        orow[lane + i * 64] = o;
    }
}

__global__ __launch_bounds__(256) void ln_k(const float* __restrict__ xin,
                                            const float* __restrict__ w,
                                            const float* __restrict__ bb,
                                            short* __restrict__ out) {
    ln_row(xin, w, bb, out, blockIdx.x * 4 + (threadIdx.x >> 6), threadIdx.x & 63);
}

// ---------- fused: 4 weight transposes (f32 [K][N] -> bf16 [N][K]) + LN1 ----------
__global__ __launch_bounds__(256) void pre_k(
        const float* __restrict__ w0, const float* __restrict__ w1,
        const float* __restrict__ w2, const float* __restrict__ w3,
        short* __restrict__ o0, short* __restrict__ o1,
        short* __restrict__ o2, short* __restrict__ o3,
        const float* __restrict__ x, const float* __restrict__ ln1w,
        const float* __restrict__ ln1b, short* __restrict__ xln) {
    int bid = blockIdx.x;
    if (bid >= 12288) {   // LN1: 1024 blocks, 4 rows each (wave per row)
        ln_row(x, ln1w, ln1b, xln, (bid - 12288) * 4 + (threadIdx.x >> 6), threadIdx.x & 63);
        return;
    }
    const float* in; short* out; int K, N, nx;
    if (bid < 3072)      { in = w0; out = o0; K = 1024; N = 3072; nx = 96; }
    else if (bid < 4096) { bid -= 3072; in = w1; out = o1; K = 1024; N = 1024; nx = 32; }
    else if (bid < 8192) { bid -= 4096; in = w2; out = o2; K = 1024; N = 4096; nx = 128; }
    else                 { bid -= 8192; in = w3; out = o3; K = 4096; N = 1024; nx = 32; }
    const int n0 = (bid % nx) * 32, k0 = (bid / nx) * 32;
    __shared__ float tile[32][33];
    const int tx = threadIdx.x & 31, ty = threadIdx.x >> 5; // ty 0..7
#pragma unroll
    for (int i = 0; i < 4; ++i) {
        const int k = ty + i * 8;
        tile[k][tx] = in[(long)(k0 + k) * N + n0 + tx];
    }
    __syncthreads();
#pragma unroll
    for (int i = 0; i < 4; ++i) {
        const int n = ty + i * 8;
        out[(long)(n0 + n) * K + k0 + tx] = f2bf(tile[tx][n]);
    }
}

// ---------- GEMM epilogue ----------
// EPI 1 GELU: tanh-form (sigmoid identity), |delta vs exact erf| < 3e-3 << bf16 tol.
template <int EPI, typename OutT>
__device__ __forceinline__ void epi_store(OutT* out, const float* resid, long oidx, float v) {
    if constexpr (EPI == 0) {
        out[oidx] = f2bf(v);
    } else if constexpr (EPI == 1) {
        const float u = v * (0.79788456080f + 0.03567740814f * v * v);
        v = v / (1.0f + __expf(-2.0f * u));
        out[oidx] = f2bf(v);
    } else {
        v += resid[oidx];
        out[oidx] = v;   // f32 store
    }
}

// ---------- GEMM 128x128, BK=32, double-buffered, 1 barrier/step ----------
template <int EPI, typename OutT>
__global__ __launch_bounds__(256) void gemm_k(const short* __restrict__ A,
                                              const short* __restrict__ Bt,
                                              const float* __restrict__ bias,
                                              const float* __restrict__ resid,
                                              OutT* __restrict__ out,
                                              int M, int N, int K) {
    __shared__ __align__(16) short sA[2][128 * 32];
    __shared__ __align__(16) short sB[2][128 * 32];
    const int tid = threadIdx.x;
    const int lane = tid & 63, wave = tid >> 6;
    const int wr = (wave >> 1) * 64, wc = (wave & 1) * 64;
    const int lrow = lane & 15, quad = lane >> 4;
    const int bm = blockIdx.y * 128, bn = blockIdx.x * 128;
    const short* Ap = A + (long)(bm + (tid >> 2)) * K + (tid & 3) * 8;
    const short* Bp = Bt + (long)(bn + (tid >> 2)) * K + (tid & 3) * 8;
    const long rowstep = (long)64 * K;

    auto stage = [&](int p, int k0) {
        gl2lds16(Ap + k0,           sA[p] + tid * 8);
        gl2lds16(Ap + rowstep + k0, sA[p] + 2048 + tid * 8);
        gl2lds16(Bp + k0,           sB[p] + tid * 8);
        gl2lds16(Bp + rowstep + k0, sB[p] + 2048 + tid * 8);
    };

    f32x4 acc[4][4] = {};
    stage(0, 0);
    const int S = K >> 5;
    for (int s = 0; s < S; ++s) {
        const int p = s & 1;
        __syncthreads();                          // drains my prefetch (hidden by prev MFMAs)
        if (s + 1 < S) stage(p ^ 1, (s + 1) << 5);
        const short* pA = sA[p];
        const short* pB = sB[p];
        s8x af[4], bfr[4];
#pragma unroll
        for (int i = 0; i < 4; ++i) af[i]  = *(const s8x*)(pA + (wr + i*16 + lrow) * 32 + quad * 8);
#pragma unroll
        for (int j = 0; j < 4; ++j) bfr[j] = *(const s8x*)(pB + (wc + j*16 + lrow) * 32 + quad * 8);
#pragma unroll
        for (int i = 0; i < 4; ++i)
#pragma unroll
            for (int j = 0; j < 4; ++j)
                acc[i][j] = __builtin_amdgcn_mfma_f32_16x16x32_bf16(af[i], bfr[j], acc[i][j], 0, 0, 0);
    }
#pragma unroll
    for (int i = 0; i < 4; ++i) {
#pragma unroll
        for (int j = 0; j < 4; ++j) {
#pragma unroll
            for (int r = 0; r < 4; ++r) {
                const int row = bm + wr + i*16 + quad*4 + r;   // C/D: row = quad*4 + reg
                const int col = bn + wc + j*16 + lrow;         // C/D: col = lane&15
                epi_store<EPI>(out, resid, (long)row * N + col, acc[i][j][r] + bias[col]);
            }
        }
    }
}

// ---------- GEMM 64x128, BK=64 (2x32 panels), double-buffered, 1 barrier/step ----------
template <int EPI, typename OutT>
__global__ __launch_bounds__(256) void gemm64_k(const short* __restrict__ A,
                                                const short* __restrict__ Bt,
                                                const float* __restrict__ bias,
                                                const float* __restrict__ resid,
                                                OutT* __restrict__ out,
                                                int M, int N, int K) {
    __shared__ __align__(16) short sA[2][2][64 * 32];
    __shared__ __align__(16) short sB[2][2][128 * 32];
    const int tid = threadIdx.x;
    const int lane = tid & 63, wave = tid >> 6;
    const int lrow = lane & 15, quad = lane >> 4;
    const int bm = blockIdx.y * 64, bn = blockIdx.x * 128;
    const short* Ap = A + (long)(bm + (tid >> 2)) * K + (tid & 3) * 8;
    const short* Bp = Bt + (long)(bn + (tid >> 2)) * K + (tid & 3) * 8;
    const long rowstep = (long)64 * K;

    auto stage = [&](int p, int k0) {
#pragma unroll
        for (int hp = 0; hp < 2; ++hp) {
            gl2lds16(Ap + k0 + hp * 32,           sA[p][hp] + tid * 8);
            gl2lds16(Bp + k0 + hp * 32,           sB[p][hp] + tid * 8);
            gl2lds16(Bp + rowstep + k0 + hp * 32, sB[p][hp] + 2048 + tid * 8);
        }
    };

    f32x4 acc[8] = {};
    stage(0, 0);
    const int S = K >> 6;
    for (int s = 0; s < S; ++s) {
        const int p = s & 1;
        __syncthreads();
        if (s + 1 < S) stage(p ^ 1, (s + 1) << 6);
#pragma unroll
        for (int hp = 0; hp < 2; ++hp) {
            const s8x af = *(const s8x*)(sA[p][hp] + (wave * 16 + lrow) * 32 + quad * 8);
#pragma unroll
            for (int j = 0; j < 8; ++j) {
                const s8x bf = *(const s8x*)(sB[p][hp] + (j * 16 + lrow) * 32 + quad * 8);
                acc[j] = __builtin_amdgcn_mfma_f32_16x16x32_bf16(af, bf, acc[j], 0, 0, 0);
            }
        }
    }
#pragma unroll
    for (int j = 0; j < 8; ++j) {
#pragma unroll
        for (int r = 0; r < 4; ++r) {
            const int row = bm + wave * 16 + quad * 4 + r;
            const int col = bn + j * 16 + lrow;
            epi_store<EPI>(out, resid, (long)row * N + col, acc[j][r] + bias[col]);
        }
    }
}

// ---------- attention common constants ----------
#define ATT_CS (0.125f * 1.4426950408889634f)  /* log2(e)/sqrt(64) */
#define ATT_C0 (14.426950408889634f)           /* 10*log2(e) fixed shift */

// ---------- paired-tile causal flash attention: B=2,H=16,T=2048,hs=64 ----------
// Pairs (bx, 31-bx): every block exactly 33 tile-iterations. No online max
// (fixed -10 shift, overflow-safe); l via MFMA-with-ones; XOR-8 swizzle on
// sK/sVt; 1 barrier per key-tile with K gl2lds prefetch + V register prefetch.
__global__ __launch_bounds__(256) void attn_k(const short* __restrict__ qkv,
                                              short* __restrict__ y) {
    const int bx = blockIdx.x;                 // 0..15
    const int b = blockIdx.y >> 4, h = blockIdx.y & 15;
    const int qtA = bx, qtB = 31 - bx;
    const int tid = threadIdx.x, lane = tid & 63, wave = tid >> 6;
    const int lrow = lane & 15, quad = lane >> 4;
    const long base = (long)b * 2048 * 3072;

    __shared__ __align__(16) short sK[2][64 * 64];
    __shared__ __align__(16) short sVt[2][64 * 64];
    __shared__ __align__(16) short sP[64 * 72];

    s8x qfA0, qfA1, qfB0, qfB1;
    {
        const short* qpA = qkv + base + (long)(qtA * 64 + wave * 16 + lrow) * 3072 + h * 64 + quad * 8;
        qfA0 = *(const s8x*)qpA; qfA1 = *(const s8x*)(qpA + 32);
        const short* qpB = qkv + base + (long)(qtB * 64 + wave * 16 + lrow) * 3072 + h * 64 + quad * 8;
        qfB0 = *(const s8x*)qpB; qfB1 = *(const s8x*)(qpB + 32);
    }
    f32x4 oA[4], oB[4], lA = {}, lB = {};
#pragma unroll
    for (int d = 0; d < 4; ++d) { oA[d] = f32x4{0.f,0.f,0.f,0.f}; oB[d] = f32x4{0.f,0.f,0.f,0.f}; }
    s8x ones;
#pragma unroll
    for (int j = 0; j < 8; ++j) ones[j] = (short)0x3F80;   // bf16 1.0

    const int srow = tid >> 3, sg = tid & 7;
    const int sw0 = ((srow & 7) ^ (srow >> 3)) & 7;
    const int sw1 = (((srow + 32) & 7) ^ ((srow + 32) >> 3)) & 7;
    const short* kbase = qkv + base + 1024 + h * 64;
    const short* vbase = qkv + base + 2048 + h * 64;

    uint4 vr0, vr1;
    auto issueK = [&](int p, int k0) {
        gl2lds16(kbase + (long)(k0 + srow) * 3072      + (sg ^ sw0) * 8, sK[p] + tid * 8);
        gl2lds16(kbase + (long)(k0 + srow + 32) * 3072 + (sg ^ sw1) * 8, sK[p] + 2048 + tid * 8);
    };
    auto loadV = [&](int k0) {
        const short* vp = vbase + (long)(k0 + srow) * 3072 + sg * 8;
        vr0 = *(const uint4*)vp;
        vr1 = *(const uint4*)(vp + 32 * 3072);
    };
    auto writeV = [&](int p) {
        const short* e0 = (const short*)&vr0;
        const short* e1 = (const short*)&vr1;
#pragma unroll
        for (int i = 0; i < 8; ++i) {
            const int d = sg * 8 + i;
            const int swd = i ^ sg;
            sVt[p][d * 64 + ( srow       ^ (swd << 3))] = e0[i];
            sVt[p][d * 64 + ((srow + 32) ^ (swd << 3))] = e1[i];
        }
    };

    auto tile_step = [&](const s8x& qf0, const s8x& qf1, const s8x* kf0, const s8x* kf1,
                         const short* pV, f32x4* o, f32x4& lacc, int qt, int kt, int k0) {
        f32x4 s[4];
#pragma unroll
        for (int ct = 0; ct < 4; ++ct) {
            f32x4 t = f32x4{0.f, 0.f, 0.f, 0.f};
            t = __builtin_amdgcn_mfma_f32_16x16x32_bf16(qf0, kf0[ct], t, 0, 0, 0);
            t = __builtin_amdgcn_mfma_f32_16x16x32_bf16(qf1, kf1[ct], t, 0, 0, 0);
            s[ct] = t;
        }
        if (kt == qt) {           // diagonal tile masking (uniform branch)
            const int qrow = qt * 64 + wave * 16 + quad * 4;
#pragma unroll
            for (int ct = 0; ct < 4; ++ct) {
                const int key = k0 + ct * 16 + lrow;
#pragma unroll
                for (int r = 0; r < 4; ++r) {
                    const float e = (key > qrow + r) ? -1e30f : fmaf(s[ct][r], ATT_CS, -ATT_C0);
                    s[ct][r] = exp2f(e);
                }
            }
        } else {
#pragma unroll
            for (int ct = 0; ct < 4; ++ct)
#pragma unroll
                for (int r = 0; r < 4; ++r)
                    s[ct][r] = exp2f(fmaf(s[ct][r], ATT_CS, -ATT_C0));
        }
#pragma unroll
        for (int ct = 0; ct < 4; ++ct)
#pragma unroll
            for (int r = 0; r < 4; ++r)
                sP[(wave * 16 + quad * 4 + r) * 72 + ct * 16 + lrow] = f2bf_trunc(s[ct][r]);
#pragma unroll
        for (int ks = 0; ks < 2; ++ks) {
            const s8x pf = *(const s8x*)(sP + (wave * 16 + lrow) * 72 + ks * 32 + quad * 8);
            lacc = __builtin_amdgcn_mfma_f32_16x16x32_bf16(pf, ones, lacc, 0, 0, 0);
#pragma unroll
            for (int dt = 0; dt < 4; ++dt) {
                const int d = dt * 16 + lrow;
                const int swd = ((d & 7) ^ (d >> 3)) & 7;
                const s8x vf = *(const s8x*)(pV + d * 64 + (((ks * 4 + quad) ^ swd) * 8));
                o[dt] = __builtin_amdgcn_mfma_f32_16x16x32_bf16(pf, vf, o[dt], 0, 0, 0);
            }
        }
    };

    issueK(0, 0);
    loadV(0);
    for (int kt = 0; kt <= qtB; ++kt) {
        const int p = kt & 1, k0 = kt * 64;
        writeV(p);
        __syncthreads();
        if (kt < qtB) { issueK(p ^ 1, k0 + 64); loadV(k0 + 64); }

        s8x kf0[4], kf1[4];
#pragma unroll
        for (int ct = 0; ct < 4; ++ct) {
            const int row = ct * 16 + lrow;
            const int swr = ((row & 7) ^ (row >> 3)) & 7;
            kf0[ct] = *(const s8x*)(sK[p] + row * 64 + ((quad ^ swr) * 8));
            kf1[ct] = *(const s8x*)(sK[p] + row * 64 + (((4 + quad) ^ swr) * 8));
        }
        if (kt <= qtA) tile_step(qfA0, qfA1, kf0, kf1, sVt[p], oA, lA, qtA, kt, k0);
        tile_step(qfB0, qfB1, kf0, kf1, sVt[p], oB, lB, qtB, kt, k0);
    }
    float rA[4], rB[4];
#pragma unroll
    for (int r = 0; r < 4; ++r) { rA[r] = 1.0f / lA[r]; rB[r] = 1.0f / lB[r]; }
#pragma unroll
    for (int dt = 0; dt < 4; ++dt) {
#pragma unroll
        for (int r = 0; r < 4; ++r) {
            const int qA = qtA * 64 + wave * 16 + quad * 4 + r;
            const int qB = qtB * 64 + wave * 16 + quad * 4 + r;
            y[((long)b * 2048 + qA) * 1024 + h * 64 + dt * 16 + lrow] = f2bf(oA[dt][r] * rA[r]);
            y[((long)b * 2048 + qB) * 1024 + h * 64 + dt * 16 + lrow] = f2bf(oB[dt][r] * rB[r]);
        }
    }
}

// ---------- launch ----------
extern "C" void kernel_launch(void* const* d_in, const int* in_sizes, int n_in,
                              void* d_out, int out_size, void* d_ws, size_t ws_size,
                              hipStream_t stream) {
    const float* x      = (const float*)d_in[0];
    const float* ln1_w  = (const float*)d_in[1];
    const float* ln1_b  = (const float*)d_in[2];
    const float* attn_w = (const float*)d_in[3];
    const float* attn_b = (const float*)d_in[4];
    const float* proj_w = (const float*)d_in[5];
    const float* proj_b = (const float*)d_in[6];
    const float* ln2_w  = (const float*)d_in[7];
    const float* ln2_b  = (const float*)d_in[8];
    const float* fc_w   = (const float*)d_in[9];
    const float* fc_b   = (const float*)d_in[10];
    const float* mlp_w  = (const float*)d_in[11];
    const float* mlp_b  = (const float*)d_in[12];

    char* ws = (char*)d_ws;
    short* attn_wt = (short*)(ws + 0);           // [3072,1024] bf16
    short* proj_wt = (short*)(ws + 6291456L);    // [1024,1024] bf16
    short* fc_wt   = (short*)(ws + 8388608L);    // [4096,1024] bf16
    short* mlp_wt  = (short*)(ws + 16777216L);   // [1024,4096] bf16
    short* slotA   = (short*)(ws + 25165824L);   // xln / y / h  [4096,1024] bf16
    short* slotB   = (short*)(ws + 33554432L);   // qkv [4096,3072] / hh [4096,4096] bf16
    // total ws use: 67,108,864 bytes (64 MB)

    short* xln  = slotA;
    short* yb   = slotA;
    short* hb   = slotA;
    short* qkvb = slotB;
    short* hh   = slotB;
    float* x1   = (float*)d_out;   // f32 residual stream lives in d_out
    float* outp = (float*)d_out;

    // transposes + LN1 fused (independent inputs)
    pre_k<<<13312, 256, 0, stream>>>(attn_w, proj_w, fc_w, mlp_w,
                                     attn_wt, proj_wt, fc_wt, mlp_wt,
                                     x, ln1_w, ln1_b, xln);

    gemm_k<0, short><<<dim3(24, 32), 256, 0, stream>>>(xln, attn_wt, attn_b, nullptr, qkvb, 4096, 3072, 1024);
    attn_k<<<dim3(16, 32), 256, 0, stream>>>(qkvb, yb);
    gemm64_k<2, float><<<dim3(8, 64), 256, 0, stream>>>(yb, proj_wt, proj_b, x, x1, 4096, 1024, 1024);
    ln_k<<<1024, 256, 0, stream>>>(x1, ln2_w, ln2_b, hb);
    gemm_k<1, short><<<dim3(32, 32), 256, 0, stream>>>(hb, fc_wt, fc_b, nullptr, hh, 4096, 4096, 1024);
    gemm64_k<3, float><<<dim3(8, 64), 256, 0, stream>>>(hh, mlp_wt, mlp_b, x1, outp, 4096, 1024, 4096);
}